// Round 4
// baseline (855.312 us; speedup 1.0000x reference)
//
#include <hip/hip_runtime.h>
#include <math.h>

// Problem constants
#define TT 4
#define BB 16
#define CC 256
#define NN 1024
#define NT 8        // spatial positions per block
#define COLS 32     // 8 n * 4 t  (layout: xs[c][n][t], t contiguous)
#define EPSF 1e-5f

#define XS(c, n, t) xs[((c) * NT + (n)) * TT + (t)]

// 4-step LIF chain, tau=2 hard-reset (v_reset=0), spike = (h >= th).
__device__ __forceinline__ void lif4(const float xin[4], float th, float s[4]) {
  float v = 0.f;
  #pragma unroll
  for (int t = 0; t < 4; ++t) {
    const float h = v + (xin[t] - v) * 0.5f;
    const bool f = (h >= th);
    s[t] = f ? 1.f : 0.f;
    v = f ? 0.f : h;
  }
}

__device__ __forceinline__ void load8(const float* __restrict__ p, int obase, float v[8]) {
  *reinterpret_cast<float4*>(&v[0]) = *reinterpret_cast<const float4*>(p + obase);
  *reinterpret_cast<float4*>(&v[4]) = *reinterpret_cast<const float4*>(p + obase + 4);
}

__device__ __forceinline__ void fma4(float4& a, float s, const float4& v) {
  a.x = fmaf(s, v.x, a.x);
  a.y = fmaf(s, v.y, a.y);
  a.z = fmaf(s, v.z, a.z);
  a.w = fmaf(s, v.w, a.w);
}

__device__ __forceinline__ void wload(const float* __restrict__ w, int obase, int cq,
                                      float4 wf[8]) {
  const float* p = w + (size_t)obase * CC + cq * 4;
  #pragma unroll
  for (int i = 0; i < 8; ++i)
    wf[i] = *reinterpret_cast<const float4*>(p + (size_t)i * CC);
}

__device__ __forceinline__ void xload(const float* xs, int nl, int cq, float4 xf[4]) {
  #pragma unroll
  for (int j = 0; j < 4; ++j)
    xf[j] = *reinterpret_cast<const float4*>(&xs[((cq * 4 + j) * NT + nl) * TT]);
}

// 128 FMAs for one c-quad; ascending-c order per accumulator (bit-exact
// across rounds: j advances c, identical fmaf chain).
__device__ __forceinline__ void quad_fma(float4 acc[8], const float4 wf[8],
                                         const float4 xf[4]) {
  #pragma unroll
  for (int i = 0; i < 8; ++i) fma4(acc[i], wf[i].x, xf[0]);
  #pragma unroll
  for (int i = 0; i < 8; ++i) fma4(acc[i], wf[i].y, xf[1]);
  #pragma unroll
  for (int i = 0; i < 8; ++i) fma4(acc[i], wf[i].z, xf[2]);
  #pragma unroll
  for (int i = 0; i < 8; ++i) fma4(acc[i], wf[i].w, xf[3]);
}

// One 256x32 GEMM pass, explicitly double-buffered: prefetch quad cq+1
// (8 dwordx4 weights + 4 ds_read_b128 x) before the 128 FMAs of quad cq.
// Named A/B buffers -> all indices compile-time (stays in registers).
__device__ __forceinline__ void gemm_pass(const float* __restrict__ w, const float* xs,
                                          int obase, int nl, float4 acc[8]) {
  #pragma unroll
  for (int i = 0; i < 8; ++i) acc[i] = make_float4(0.f, 0.f, 0.f, 0.f);

  float4 wA[8], xA[4], wB[8], xB[4];
  wload(w, obase, 0, wA);
  xload(xs, nl, 0, xA);
  #pragma unroll 1
  for (int cq = 0; cq < 62; cq += 2) {
    wload(w, obase, cq + 1, wB);
    xload(xs, nl, cq + 1, xB);
    quad_fma(acc, wA, xA);
    wload(w, obase, cq + 2, wA);
    xload(xs, nl, cq + 2, xA);
    quad_fma(acc, wB, xB);
  }
  wload(w, obase, 63, wB);
  xload(xs, nl, 63, xB);
  quad_fma(acc, wA, xA);
  quad_fma(acc, wB, xB);
}

__global__ __launch_bounds__(256, 3)
void pushpull_fused4(const float* __restrict__ x,
                     const float* __restrict__ q_w, const float* __restrict__ q_gamma,
                     const float* __restrict__ q_beta, const float* __restrict__ q_mean,
                     const float* __restrict__ q_var,
                     const float* __restrict__ k_w, const float* __restrict__ k_gamma,
                     const float* __restrict__ k_beta, const float* __restrict__ k_mean,
                     const float* __restrict__ k_var,
                     const float* __restrict__ proj_w, const float* __restrict__ proj_b,
                     const float* __restrict__ p_gamma, const float* __restrict__ p_beta,
                     const float* __restrict__ p_mean, const float* __restrict__ p_var,
                     float* __restrict__ out) {
  __shared__ float xs[CC * COLS];   // 32 KB: xs[c][n][t]

  const int tid = threadIdx.x;
  // Chunked XCD swizzle (bijective: 2048 = 8*256): adjacent n-tiles -> same XCD
  // so half-line x fetches and out writes merge in that XCD's L2.
  const int bid = (int)blockIdx.x;
  const int lid = ((bid & 7) << 8) | (bid >> 3);
  const int b     = lid >> 7;                   // 16 batches
  const int n0    = (lid & 127) * NT;           // 128 spatial tiles of 8
  const int oblk  = tid >> 3;                   // 32 o-blocks of 8 channels
  const int nl    = tid & 7;                    // spatial index in tile
  const int obase = oblk * 8;

  // ---- Stage x tile: float4 global reads -> scalar LDS writes [c][n][t] ----
  #pragma unroll
  for (int rep = 0; rep < 8; ++rep) {
    const int idx4 = rep * 256 + tid;
    const int n4 = (idx4 & 1) * 4;
    const int t  = (idx4 >> 1) & 3;
    const int c  = idx4 >> 3;
    const float4 v = *reinterpret_cast<const float4*>(
        x + (((size_t)t * BB + b) * CC + c) * NN + n0 + n4);
    XS(c, n4 + 0, t) = v.x;
    XS(c, n4 + 1, t) = v.y;
    XS(c, n4 + 2, t) = v.z;
    XS(c, n4 + 3, t) = v.w;
  }
  __syncthreads();

  float d[4] = {0.f, 0.f, 0.f, 0.f};

  // ---- q pass: GEMM + BN + push/pull LIF -> d[t] partial head sums ----
  {
    float4 acc[8];
    gemm_pass(q_w, xs, obase, nl, acc);
    float g[8], be[8], mn[8], vr[8];
    load8(q_gamma, obase, g);  load8(q_beta, obase, be);
    load8(q_mean,  obase, mn); load8(q_var,  obase, vr);
    #pragma unroll
    for (int i = 0; i < 8; ++i) {
      const float inv = g[i] / sqrtf(vr[i] + EPSF);
      const float* a = &acc[i].x;
      float qv[4], nqv[4], se[4], si[4];
      #pragma unroll
      for (int t = 0; t < 4; ++t) {
        qv[t]  = (a[t] - mn[i]) * inv + be[i];
        nqv[t] = -qv[t];
      }
      lif4(qv,  1.0f, se);
      lif4(nqv, 1.0f, si);
      #pragma unroll
      for (int t = 0; t < 4; ++t) d[t] += se[t] - si[t];   // exact small ints
    }
  }

  // ---- k pass: GEMM + BN + LIF -> binary mask ----
  unsigned kmask = 0u;
  {
    float4 acc[8];
    gemm_pass(k_w, xs, obase, nl, acc);
    float g[8], be[8], mn[8], vr[8];
    load8(k_gamma, obase, g);  load8(k_beta, obase, be);
    load8(k_mean,  obase, mn); load8(k_var,  obase, vr);
    #pragma unroll
    for (int i = 0; i < 8; ++i) {
      const float inv = g[i] / sqrtf(vr[i] + EPSF);
      const float* a = &acc[i].x;
      float kv[4], sk[4];
      #pragma unroll
      for (int t = 0; t < 4; ++t) kv[t] = (a[t] - mn[i]) * inv + be[i];
      lif4(kv, 1.0f, sk);
      #pragma unroll
      for (int t = 0; t < 4; ++t)
        kmask |= (sk[t] != 0.f) ? (1u << (i * 4 + t)) : 0u;
    }
  }

  // ---- head reduce (4 oblks = 32 ch per head) + attention LIF gate ----
  float at[4];
  {
    #pragma unroll
    for (int t = 0; t < 4; ++t) {
      float v = d[t];
      v += __shfl_xor(v, 8);    // oblk bit0
      v += __shfl_xor(v, 16);   // oblk bit1
      d[t] = v;                 // exact integer sums
    }
    lif4(d, 0.5f, at);
  }

  __syncthreads();  // all xs reads for q/k done
  // ---- x_one = attn & k_s (binary), overwrite xs in place (b128 writes) ----
  #pragma unroll
  for (int i = 0; i < 8; ++i) {
    float4 v;
    v.x = ((kmask >> (i * 4 + 0)) & 1u) ? at[0] : 0.f;
    v.y = ((kmask >> (i * 4 + 1)) & 1u) ? at[1] : 0.f;
    v.z = ((kmask >> (i * 4 + 2)) & 1u) ? at[2] : 0.f;
    v.w = ((kmask >> (i * 4 + 3)) & 1u) ? at[3] : 0.f;
    *reinterpret_cast<float4*>(&XS(obase + i, nl, 0)) = v;
  }
  __syncthreads();

  // ---- proj pass: GEMM + bias + BN + final LIF + store ----
  {
    float4 acc[8];
    gemm_pass(proj_w, xs, obase, nl, acc);
    float g[8], be[8], mn[8], vr[8], pb[8];
    load8(p_gamma, obase, g);  load8(p_beta, obase, be);
    load8(p_mean,  obase, mn); load8(p_var,  obase, vr);
    load8(proj_b,  obase, pb);
    #pragma unroll
    for (int i = 0; i < 8; ++i) {
      const float inv = g[i] / sqrtf(vr[i] + EPSF);
      const float* a = &acc[i].x;
      float pv[4], sp[4];
      #pragma unroll
      for (int t = 0; t < 4; ++t)
        pv[t] = ((a[t] + pb[i]) - mn[i]) * inv + be[i];
      lif4(pv, 1.0f, sp);
      #pragma unroll
      for (int t = 0; t < 4; ++t)
        out[(((size_t)t * BB + b) * CC + obase + i) * NN + n0 + nl] = sp[t];
    }
  }
}

extern "C" void kernel_launch(void* const* d_in, const int* in_sizes, int n_in,
                              void* d_out, int out_size, void* d_ws, size_t ws_size,
                              hipStream_t stream) {
  const float* x       = (const float*)d_in[0];
  const float* q_w     = (const float*)d_in[1];
  const float* q_gamma = (const float*)d_in[2];
  const float* q_beta  = (const float*)d_in[3];
  const float* q_mean  = (const float*)d_in[4];
  const float* q_var   = (const float*)d_in[5];
  const float* k_w     = (const float*)d_in[6];
  const float* k_gamma = (const float*)d_in[7];
  const float* k_beta  = (const float*)d_in[8];
  const float* k_mean  = (const float*)d_in[9];
  const float* k_var   = (const float*)d_in[10];
  const float* proj_w  = (const float*)d_in[11];
  const float* proj_b  = (const float*)d_in[12];
  const float* p_gamma = (const float*)d_in[13];
  const float* p_beta  = (const float*)d_in[14];
  const float* p_mean  = (const float*)d_in[15];
  const float* p_var   = (const float*)d_in[16];
  float* out = (float*)d_out;

  dim3 grid(BB * (NN / NT));   // 16 * 128 = 2048 blocks
  dim3 block(256);
  pushpull_fused4<<<grid, block, 0, stream>>>(
      x, q_w, q_gamma, q_beta, q_mean, q_var,
      k_w, k_gamma, k_beta, k_mean, k_var,
      proj_w, proj_b, p_gamma, p_beta, p_mean, p_var, out);
}

// Round 5
// 580.384 us; speedup vs baseline: 1.4737x; 1.4737x over previous
//
#include <hip/hip_runtime.h>
#include <math.h>

// Problem constants
#define TT 4
#define BB 16
#define CC 256
#define NN 1024
#define NT 8        // spatial positions per block
#define COLS 32     // 8 n * 4 t  (layout: xs[c][n][t], t contiguous)
#define EPSF 1e-5f

#define XS(c, n, t) xs[((c) * NT + (n)) * TT + (t)]

// 4-step LIF chain, tau=2 hard-reset (v_reset=0), spike = (h >= th).
// h = v + (x - v)/2 exactly as reference (div by 2 == *0.5, exact).
__device__ __forceinline__ void lif4(const float xin[4], float th, float s[4]) {
  float v = 0.f;
  #pragma unroll
  for (int t = 0; t < 4; ++t) {
    const float h = v + (xin[t] - v) * 0.5f;
    const bool f = (h >= th);
    s[t] = f ? 1.f : 0.f;
    v = f ? 0.f : h;
  }
}

__device__ __forceinline__ void load8(const float* __restrict__ p, int obase, float v[8]) {
  *reinterpret_cast<float4*>(&v[0]) = *reinterpret_cast<const float4*>(p + obase);
  *reinterpret_cast<float4*>(&v[4]) = *reinterpret_cast<const float4*>(p + obase + 4);
}

__device__ __forceinline__ void fma4(float4& a, float s, const float4& v) {
  a.x = fmaf(s, v.x, a.x);
  a.y = fmaf(s, v.y, a.y);
  a.z = fmaf(s, v.z, a.z);
  a.w = fmaf(s, v.w, a.w);
}

// One 256x32 GEMM pass: acc[i].{x..w} = sum_c w[obase+i][c] * xs[c][nl][t].
// Weights per-lane dwordx4 (L2-resident, 8-way same-address merge in TA);
// x via ds_read_b128 (4 t-values per read, conflict-free broadcast).
// FMA order over c ascending == rounds 1-4 bit-exactly. No explicit
// double-buffer arrays (R4 lesson: they spill); latency hidden by TLP.
__device__ __forceinline__ void gemm_pass(const float* __restrict__ w, const float* xs,
                                          int obase, int nl, float4 acc[8]) {
  #pragma unroll
  for (int i = 0; i < 8; ++i) acc[i] = make_float4(0.f, 0.f, 0.f, 0.f);

  #pragma unroll 2
  for (int cq = 0; cq < CC / 4; ++cq) {
    const int c0 = cq * 4;
    float4 wf[8];
    #pragma unroll
    for (int i = 0; i < 8; ++i)
      wf[i] = *reinterpret_cast<const float4*>(w + (size_t)(obase + i) * CC + c0);
    float4 xf[4];
    #pragma unroll
    for (int j = 0; j < 4; ++j)
      xf[j] = *reinterpret_cast<const float4*>(&xs[((c0 + j) * NT + nl) * TT]);
    #pragma unroll
    for (int i = 0; i < 8; ++i) fma4(acc[i], wf[i].x, xf[0]);
    #pragma unroll
    for (int i = 0; i < 8; ++i) fma4(acc[i], wf[i].y, xf[1]);
    #pragma unroll
    for (int i = 0; i < 8; ++i) fma4(acc[i], wf[i].z, xf[2]);
    #pragma unroll
    for (int i = 0; i < 8; ++i) fma4(acc[i], wf[i].w, xf[3]);
  }
}

__global__ __launch_bounds__(256, 5)   // 5 blocks/CU (LDS 160/32), VGPR cap 102
void pushpull_fused5(const float* __restrict__ x,
                     const float* __restrict__ q_w, const float* __restrict__ q_gamma,
                     const float* __restrict__ q_beta, const float* __restrict__ q_mean,
                     const float* __restrict__ q_var,
                     const float* __restrict__ k_w, const float* __restrict__ k_gamma,
                     const float* __restrict__ k_beta, const float* __restrict__ k_mean,
                     const float* __restrict__ k_var,
                     const float* __restrict__ proj_w, const float* __restrict__ proj_b,
                     const float* __restrict__ p_gamma, const float* __restrict__ p_beta,
                     const float* __restrict__ p_mean, const float* __restrict__ p_var,
                     float* __restrict__ out) {
  __shared__ float xs[CC * COLS];   // 32 KB: xs[c][n][t]

  const int tid = threadIdx.x;
  // Chunked XCD swizzle (bijective: 2048 = 8*256): consecutive lids (neighbor
  // n-tiles) land on the same XCD and are temporally adjacent -> half-line
  // out writes and shared x lines merge in that XCD's L2.
  const int bid = (int)blockIdx.x;
  const int lid = ((bid & 7) << 8) | (bid >> 3);
  const int b     = lid >> 7;                   // 16 batches
  const int n0    = (lid & 127) * NT;           // 128 spatial tiles of 8
  const int oblk  = tid >> 3;                   // 32 o-blocks of 8 channels
  const int nl    = tid & 7;                    // spatial index in tile
  const int obase = oblk * 8;

  // ---- Stage x tile: float4 global reads -> scalar LDS writes [c][n][t] ----
  #pragma unroll
  for (int rep = 0; rep < 8; ++rep) {
    const int idx4 = rep * 256 + tid;
    const int n4 = (idx4 & 1) * 4;
    const int t  = (idx4 >> 1) & 3;
    const int c  = idx4 >> 3;
    const float4 v = *reinterpret_cast<const float4*>(
        x + (((size_t)t * BB + b) * CC + c) * NN + n0 + n4);
    XS(c, n4 + 0, t) = v.x;
    XS(c, n4 + 1, t) = v.y;
    XS(c, n4 + 2, t) = v.z;
    XS(c, n4 + 3, t) = v.w;
  }
  __syncthreads();

  float d[4] = {0.f, 0.f, 0.f, 0.f};

  // ---- q pass: GEMM + BN + push/pull LIF -> d[t] partial head sums ----
  {
    float4 acc[8];
    gemm_pass(q_w, xs, obase, nl, acc);
    float g[8], be[8], mn[8], vr[8];
    load8(q_gamma, obase, g);  load8(q_beta, obase, be);
    load8(q_mean,  obase, mn); load8(q_var,  obase, vr);
    #pragma unroll
    for (int i = 0; i < 8; ++i) {
      const float inv = g[i] / sqrtf(vr[i] + EPSF);
      const float* a = &acc[i].x;
      float qv[4], nqv[4], se[4], si[4];
      #pragma unroll
      for (int t = 0; t < 4; ++t) {
        qv[t]  = (a[t] - mn[i]) * inv + be[i];
        nqv[t] = -qv[t];
      }
      lif4(qv,  1.0f, se);
      lif4(nqv, 1.0f, si);
      #pragma unroll
      for (int t = 0; t < 4; ++t) d[t] += se[t] - si[t];   // exact small ints
    }
  }

  // ---- k pass: GEMM + BN + LIF -> binary mask ----
  unsigned kmask = 0u;
  {
    float4 acc[8];
    gemm_pass(k_w, xs, obase, nl, acc);
    float g[8], be[8], mn[8], vr[8];
    load8(k_gamma, obase, g);  load8(k_beta, obase, be);
    load8(k_mean,  obase, mn); load8(k_var,  obase, vr);
    #pragma unroll
    for (int i = 0; i < 8; ++i) {
      const float inv = g[i] / sqrtf(vr[i] + EPSF);
      const float* a = &acc[i].x;
      float kv[4], sk[4];
      #pragma unroll
      for (int t = 0; t < 4; ++t) kv[t] = (a[t] - mn[i]) * inv + be[i];
      lif4(kv, 1.0f, sk);
      #pragma unroll
      for (int t = 0; t < 4; ++t)
        kmask |= (sk[t] != 0.f) ? (1u << (i * 4 + t)) : 0u;
    }
  }

  // ---- head reduce (4 oblks = 32 ch per head) + attention LIF gate ----
  float at[4];
  {
    #pragma unroll
    for (int t = 0; t < 4; ++t) {
      float v = d[t];
      v += __shfl_xor(v, 8);    // oblk bit0
      v += __shfl_xor(v, 16);   // oblk bit1
      d[t] = v;                 // exact integer sums
    }
    lif4(d, 0.5f, at);
  }

  __syncthreads();  // all xs reads for q/k done
  // ---- x_one = attn & k_s (binary), overwrite xs in place (b128 writes) ----
  #pragma unroll
  for (int i = 0; i < 8; ++i) {
    float4 v;
    v.x = ((kmask >> (i * 4 + 0)) & 1u) ? at[0] : 0.f;
    v.y = ((kmask >> (i * 4 + 1)) & 1u) ? at[1] : 0.f;
    v.z = ((kmask >> (i * 4 + 2)) & 1u) ? at[2] : 0.f;
    v.w = ((kmask >> (i * 4 + 3)) & 1u) ? at[3] : 0.f;
    *reinterpret_cast<float4*>(&XS(obase + i, nl, 0)) = v;
  }
  __syncthreads();

  // ---- proj pass: GEMM + bias + BN + final LIF + store ----
  {
    float4 acc[8];
    gemm_pass(proj_w, xs, obase, nl, acc);
    float g[8], be[8], mn[8], vr[8], pb[8];
    load8(p_gamma, obase, g);  load8(p_beta, obase, be);
    load8(p_mean,  obase, mn); load8(p_var,  obase, vr);
    load8(proj_b,  obase, pb);
    #pragma unroll
    for (int i = 0; i < 8; ++i) {
      const float inv = g[i] / sqrtf(vr[i] + EPSF);
      const float* a = &acc[i].x;
      float pv[4], sp[4];
      #pragma unroll
      for (int t = 0; t < 4; ++t)
        pv[t] = ((a[t] + pb[i]) - mn[i]) * inv + be[i];
      lif4(pv, 1.0f, sp);
      #pragma unroll
      for (int t = 0; t < 4; ++t)
        out[(((size_t)t * BB + b) * CC + obase + i) * NN + n0 + nl] = sp[t];
    }
  }
}

extern "C" void kernel_launch(void* const* d_in, const int* in_sizes, int n_in,
                              void* d_out, int out_size, void* d_ws, size_t ws_size,
                              hipStream_t stream) {
  const float* x       = (const float*)d_in[0];
  const float* q_w     = (const float*)d_in[1];
  const float* q_gamma = (const float*)d_in[2];
  const float* q_beta  = (const float*)d_in[3];
  const float* q_mean  = (const float*)d_in[4];
  const float* q_var   = (const float*)d_in[5];
  const float* k_w     = (const float*)d_in[6];
  const float* k_gamma = (const float*)d_in[7];
  const float* k_beta  = (const float*)d_in[8];
  const float* k_mean  = (const float*)d_in[9];
  const float* k_var   = (const float*)d_in[10];
  const float* proj_w  = (const float*)d_in[11];
  const float* proj_b  = (const float*)d_in[12];
  const float* p_gamma = (const float*)d_in[13];
  const float* p_beta  = (const float*)d_in[14];
  const float* p_mean  = (const float*)d_in[15];
  const float* p_var   = (const float*)d_in[16];
  float* out = (float*)d_out;

  dim3 grid(BB * (NN / NT));   // 16 * 128 = 2048 blocks
  dim3 block(256);
  pushpull_fused5<<<grid, block, 0, stream>>>(
      x, q_w, q_gamma, q_beta, q_mean, q_var,
      k_w, k_gamma, k_beta, k_mean, k_var,
      proj_w, proj_b, p_gamma, p_beta, p_mean, p_var, out);
}

// Round 6
// 575.423 us; speedup vs baseline: 1.4864x; 1.0086x over previous
//
#include <hip/hip_runtime.h>
#include <math.h>

// Problem constants
#define TT 4
#define BB 16
#define CC 256
#define NN 1024
#define NT 8        // spatial positions per block
#define COLS 32     // 8 n * 4 t  (layout: xs[c][n][t], t contiguous)
#define EPSF 1e-5f

#define XS(c, n, t) xs[((c) * NT + (n)) * TT + (t)]

// 4-step LIF chain, tau=2 hard-reset (v_reset=0), spike = (h >= th).
// h = v + (x - v)/2 exactly as reference (div by 2 == *0.5, exact).
__device__ __forceinline__ void lif4(const float xin[4], float th, float s[4]) {
  float v = 0.f;
  #pragma unroll
  for (int t = 0; t < 4; ++t) {
    const float h = v + (xin[t] - v) * 0.5f;
    const bool f = (h >= th);
    s[t] = f ? 1.f : 0.f;
    v = f ? 0.f : h;
  }
}

__device__ __forceinline__ void load4(const float* __restrict__ p, int obase, float v[4]) {
  *reinterpret_cast<float4*>(&v[0]) = *reinterpret_cast<const float4*>(p + obase);
}

__device__ __forceinline__ void fma4(float4& a, float s, const float4& v) {
  a.x = fmaf(s, v.x, a.x);
  a.y = fmaf(s, v.y, a.y);
  a.z = fmaf(s, v.z, a.z);
  a.w = fmaf(s, v.w, a.w);
}

// One 256-deep GEMM pass for a 4-out-ch x 4-t micro-tile at spatial nl.
// acc[i].{x..w} = sum_c w[obase+i][c] * xs[c][nl][t], t=0..3.
// Weights per-lane dwordx4 (8 rows/wave, L1-merged); x via ds_read_b128.
// FMA order over c ascending == rounds 1-5 bit-exactly.
__device__ __forceinline__ void gemm_pass(const float* __restrict__ w, const float* xs,
                                          int obase, int nl, float4 acc[4]) {
  #pragma unroll
  for (int i = 0; i < 4; ++i) acc[i] = make_float4(0.f, 0.f, 0.f, 0.f);

  #pragma unroll 2
  for (int cq = 0; cq < CC / 4; ++cq) {
    const int c0 = cq * 4;
    float4 wf[4];
    #pragma unroll
    for (int i = 0; i < 4; ++i)
      wf[i] = *reinterpret_cast<const float4*>(w + (size_t)(obase + i) * CC + c0);
    float4 xf[4];
    #pragma unroll
    for (int j = 0; j < 4; ++j)
      xf[j] = *reinterpret_cast<const float4*>(&xs[((c0 + j) * NT + nl) * TT]);
    #pragma unroll
    for (int i = 0; i < 4; ++i) fma4(acc[i], wf[i].x, xf[0]);
    #pragma unroll
    for (int i = 0; i < 4; ++i) fma4(acc[i], wf[i].y, xf[1]);
    #pragma unroll
    for (int i = 0; i < 4; ++i) fma4(acc[i], wf[i].z, xf[2]);
    #pragma unroll
    for (int i = 0; i < 4; ++i) fma4(acc[i], wf[i].w, xf[3]);
  }
}

// 512 threads/block = 8 waves; 4 blocks/CU (LDS 4x32=128 <= 160 KB) ->
// 32 waves/CU (8/SIMD). VGPR cap 64: micro-tile needs ~56.
__global__ __launch_bounds__(512, 8)
void pushpull_fused6(const float* __restrict__ x,
                     const float* __restrict__ q_w, const float* __restrict__ q_gamma,
                     const float* __restrict__ q_beta, const float* __restrict__ q_mean,
                     const float* __restrict__ q_var,
                     const float* __restrict__ k_w, const float* __restrict__ k_gamma,
                     const float* __restrict__ k_beta, const float* __restrict__ k_mean,
                     const float* __restrict__ k_var,
                     const float* __restrict__ proj_w, const float* __restrict__ proj_b,
                     const float* __restrict__ p_gamma, const float* __restrict__ p_beta,
                     const float* __restrict__ p_mean, const float* __restrict__ p_var,
                     float* __restrict__ out) {
  __shared__ float xs[CC * COLS];   // 32 KB: xs[c][n][t]

  const int tid = threadIdx.x;
  // Chunked XCD swizzle (bijective: 2048 = 8*256): neighbor n-tiles share an
  // XCD L2 -> half-line x fetches and out writes merge.
  const int bid = (int)blockIdx.x;
  const int lid = ((bid & 7) << 8) | (bid >> 3);
  const int b     = lid >> 7;                   // 16 batches
  const int n0    = (lid & 127) * NT;           // 128 spatial tiles of 8
  const int oblk  = tid >> 3;                   // 64 o-blocks of 4 channels
  const int nl    = tid & 7;                    // spatial index in tile
  const int obase = oblk * 4;
  // wave w == head w: lanes i8*8+nl, i8=0..7 cover the head's 8 o-blocks.

  // ---- Stage x tile: float4 global reads -> scalar LDS writes [c][n][t] ----
  #pragma unroll
  for (int rep = 0; rep < 4; ++rep) {
    const int idx4 = rep * 512 + tid;
    const int n4 = (idx4 & 1) * 4;
    const int t  = (idx4 >> 1) & 3;
    const int c  = idx4 >> 3;
    const float4 v = *reinterpret_cast<const float4*>(
        x + (((size_t)t * BB + b) * CC + c) * NN + n0 + n4);
    XS(c, n4 + 0, t) = v.x;
    XS(c, n4 + 1, t) = v.y;
    XS(c, n4 + 2, t) = v.z;
    XS(c, n4 + 3, t) = v.w;
  }
  __syncthreads();

  float d[4] = {0.f, 0.f, 0.f, 0.f};

  // ---- q pass: GEMM + BN + push/pull LIF -> d[t] partial head sums ----
  {
    float4 acc[4];
    gemm_pass(q_w, xs, obase, nl, acc);
    float g[4], be[4], mn[4], vr[4];
    load4(q_gamma, obase, g);  load4(q_beta, obase, be);
    load4(q_mean,  obase, mn); load4(q_var,  obase, vr);
    #pragma unroll
    for (int i = 0; i < 4; ++i) {
      const float inv = g[i] / sqrtf(vr[i] + EPSF);
      const float* a = &acc[i].x;
      float qv[4], nqv[4], se[4], si[4];
      #pragma unroll
      for (int t = 0; t < 4; ++t) {
        qv[t]  = (a[t] - mn[i]) * inv + be[i];
        nqv[t] = -qv[t];
      }
      lif4(qv,  1.0f, se);
      lif4(nqv, 1.0f, si);
      #pragma unroll
      for (int t = 0; t < 4; ++t) d[t] += se[t] - si[t];   // exact small ints
    }
  }

  // ---- k pass: GEMM + BN + LIF -> binary mask (bit i*4+t) ----
  unsigned kmask = 0u;
  {
    float4 acc[4];
    gemm_pass(k_w, xs, obase, nl, acc);
    float g[4], be[4], mn[4], vr[4];
    load4(k_gamma, obase, g);  load4(k_beta, obase, be);
    load4(k_mean,  obase, mn); load4(k_var,  obase, vr);
    #pragma unroll
    for (int i = 0; i < 4; ++i) {
      const float inv = g[i] / sqrtf(vr[i] + EPSF);
      const float* a = &acc[i].x;
      float kv[4], sk[4];
      #pragma unroll
      for (int t = 0; t < 4; ++t) kv[t] = (a[t] - mn[i]) * inv + be[i];
      lif4(kv, 1.0f, sk);
      #pragma unroll
      for (int t = 0; t < 4; ++t)
        kmask |= (sk[t] != 0.f) ? (1u << (i * 4 + t)) : 0u;
    }
  }

  // ---- head reduce (8 oblks x 4 ch = 32 ch, in-wave) + attention gate ----
  float at[4];
  {
    #pragma unroll
    for (int t = 0; t < 4; ++t) {
      float v = d[t];
      v += __shfl_xor(v, 8);    // lane bits 3..5 span the head's 8 o-blocks
      v += __shfl_xor(v, 16);
      v += __shfl_xor(v, 32);
      d[t] = v;                 // exact integer sums
    }
    lif4(d, 0.5f, at);
  }

  __syncthreads();  // all xs reads for q/k done
  // ---- x_one = attn & k_s (binary), overwrite xs in place (b128 writes) ----
  #pragma unroll
  for (int i = 0; i < 4; ++i) {
    float4 v;
    v.x = ((kmask >> (i * 4 + 0)) & 1u) ? at[0] : 0.f;
    v.y = ((kmask >> (i * 4 + 1)) & 1u) ? at[1] : 0.f;
    v.z = ((kmask >> (i * 4 + 2)) & 1u) ? at[2] : 0.f;
    v.w = ((kmask >> (i * 4 + 3)) & 1u) ? at[3] : 0.f;
    *reinterpret_cast<float4*>(&XS(obase + i, nl, 0)) = v;
  }
  __syncthreads();

  // ---- proj pass: GEMM + bias + BN + final LIF + store ----
  {
    float4 acc[4];
    gemm_pass(proj_w, xs, obase, nl, acc);
    float g[4], be[4], mn[4], vr[4], pb[4];
    load4(p_gamma, obase, g);  load4(p_beta, obase, be);
    load4(p_mean,  obase, mn); load4(p_var,  obase, vr);
    load4(proj_b,  obase, pb);
    #pragma unroll
    for (int i = 0; i < 4; ++i) {
      const float inv = g[i] / sqrtf(vr[i] + EPSF);
      const float* a = &acc[i].x;
      float pv[4], sp[4];
      #pragma unroll
      for (int t = 0; t < 4; ++t)
        pv[t] = ((a[t] + pb[i]) - mn[i]) * inv + be[i];
      lif4(pv, 1.0f, sp);
      #pragma unroll
      for (int t = 0; t < 4; ++t)
        out[(((size_t)t * BB + b) * CC + obase + i) * NN + n0 + nl] = sp[t];
    }
  }
}

extern "C" void kernel_launch(void* const* d_in, const int* in_sizes, int n_in,
                              void* d_out, int out_size, void* d_ws, size_t ws_size,
                              hipStream_t stream) {
  const float* x       = (const float*)d_in[0];
  const float* q_w     = (const float*)d_in[1];
  const float* q_gamma = (const float*)d_in[2];
  const float* q_beta  = (const float*)d_in[3];
  const float* q_mean  = (const float*)d_in[4];
  const float* q_var   = (const float*)d_in[5];
  const float* k_w     = (const float*)d_in[6];
  const float* k_gamma = (const float*)d_in[7];
  const float* k_beta  = (const float*)d_in[8];
  const float* k_mean  = (const float*)d_in[9];
  const float* k_var   = (const float*)d_in[10];
  const float* proj_w  = (const float*)d_in[11];
  const float* proj_b  = (const float*)d_in[12];
  const float* p_gamma = (const float*)d_in[13];
  const float* p_beta  = (const float*)d_in[14];
  const float* p_mean  = (const float*)d_in[15];
  const float* p_var   = (const float*)d_in[16];
  float* out = (float*)d_out;

  dim3 grid(BB * (NN / NT));   // 16 * 128 = 2048 blocks
  dim3 block(512);             // 8 waves; wave == head
  pushpull_fused6<<<grid, block, 0, stream>>>(
      x, q_w, q_gamma, q_beta, q_mean, q_var,
      k_w, k_gamma, k_beta, k_mean, k_var,
      proj_w, proj_b, p_gamma, p_beta, p_mean, p_var, out);
}